// Round 1
// baseline (567.830 us; speedup 1.0000x reference)
//
#include <hip/hip_runtime.h>

// Problem constants
#define B_    64
#define IN_   1024
#define OUT_  1024
#define NROWS (B_ * OUT_)            // 65536
#define NW_ELEMS 67108864.0          // B*OUT*IN

// math constants
#define LOG_SQRT_2PI   0.9189385332046727
#define LOG_SQRT_2PI_F 0.9189385332046727f
// CA = log(0.5) - log(sqrt(2pi)) - log(sigma1=1)
#define CA (-1.6120857137646178f)
// CB = log(0.5) - log(sqrt(2pi)) - log(sigma2=0.002)
#define CB (4.6025223846575735f)
// DC = CA - CB
#define DC (-6.2146080984221913f)
// 1/(2*sigma2^2) = 125000
#define INV2S2 (125000.0f)
// INV2S2 - 0.5
#define DSLOPE (124999.5f)

// acc layout (doubles in d_ws):
// [0..63]   prior_w partial slots
// [64..127] sum(eps_w^2) partial slots
// [128]     sum(log sigma_w) over (O,I)
// [129]     prior_b
// [130]     posterior_b
#define N_ACC 131

__device__ __forceinline__ float wred(float v) {
#pragma unroll
    for (int o = 32; o > 0; o >>= 1) v += __shfl_down(v, o, 64);
    return v;
}

__global__ __launch_bounds__(256) void k_zero(double* __restrict__ acc) {
    int t = threadIdx.x;
    if (t < N_ACC) acc[t] = 0.0;
}

// sum over (O,I) of log(softplus(weight_rho))
__global__ __launch_bounds__(256) void k_logsig(const float* __restrict__ wrho,
                                                double* __restrict__ acc) {
    int t = blockIdx.x * 256 + threadIdx.x;       // 0..262143, 4 elems each
    float4 r = ((const float4*)wrho)[t];
    float s = 0.f;
    s += logf(log1pf(expf(r.x)));
    s += logf(log1pf(expf(r.y)));
    s += logf(log1pf(expf(r.z)));
    s += logf(log1pf(expf(r.w)));
    s = wred(s);
    __shared__ float sm[4];
    if ((threadIdx.x & 63) == 0) sm[threadIdx.x >> 6] = s;
    __syncthreads();
    if (threadIdx.x == 0)
        atomicAdd(&acc[128], (double)(sm[0] + sm[1] + sm[2] + sm[3]));
}

// one component of the fused per-element work
#define COMP(EC, XC, SGC, MUC)                                                \
    {                                                                         \
        float w  = fmaf(SGC, EC, MUC);                                        \
        dot      = fmaf(w, XC, dot);                                          \
        float v2 = w * w;                                                     \
        float aa = fmaf(-0.5f, v2, CA);                                       \
        float bb = fmaf(-INV2S2, v2, CB);                                     \
        float dd = fmaf(DSLOPE, v2, DC);                                      \
        prior += fmaxf(aa, bb) + log1pf(expf(-fabsf(dd)));                    \
        eps2 = fmaf(EC, EC, eps2);                                            \
    }

// main fused pass over eps_w: out = einsum + weight prior + sum(eps^2)
__global__ __launch_bounds__(256) void k_main(const float* __restrict__ x,
                                              const float* __restrict__ wmu,
                                              const float* __restrict__ wrho,
                                              const float* __restrict__ epsw,
                                              float* __restrict__ out,
                                              double* __restrict__ acc) {
    const int lane = threadIdx.x & 63;
    const int wid  = threadIdx.x >> 6;
    const int gw   = blockIdx.x * 4 + wid;  // global wave id, 0..16383
    const int o    = gw & 1023;             // output column (fixed per wave)
    const int b0   = gw >> 10;              // 0..15

    const float4* mp = (const float4*)(wmu  + (size_t)o * IN_);
    const float4* rp = (const float4*)(wrho + (size_t)o * IN_);

    // hoist sigma & mu for this o: computed once, reused for 4 batch rows
    float4 sg[4], mu[4];
#pragma unroll
    for (int k = 0; k < 4; ++k) {
        float4 r = rp[lane + 64 * k];
        mu[k]    = mp[lane + 64 * k];
        sg[k].x  = log1pf(expf(r.x));
        sg[k].y  = log1pf(expf(r.y));
        sg[k].z  = log1pf(expf(r.z));
        sg[k].w  = log1pf(expf(r.w));
    }

    float prior = 0.f, eps2 = 0.f;
#pragma unroll
    for (int j = 0; j < 4; ++j) {
        const int b      = b0 + 16 * j;
        const size_t row = ((size_t)b << 10) | (size_t)o;
        const float4* ep = (const float4*)(epsw + row * IN_);
        const float4* xp = (const float4*)(x + (size_t)b * IN_);
        float dot = 0.f;
#pragma unroll
        for (int k = 0; k < 4; ++k) {
            float4 e  = ep[lane + 64 * k];
            float4 xx = xp[lane + 64 * k];
            COMP(e.x, xx.x, sg[k].x, mu[k].x)
            COMP(e.y, xx.y, sg[k].y, mu[k].y)
            COMP(e.z, xx.z, sg[k].z, mu[k].z)
            COMP(e.w, xx.w, sg[k].w, mu[k].w)
        }
        dot = wred(dot);
        if (lane == 0) out[row] = dot;   // bias added by k_bias
    }

    prior = wred(prior);
    eps2  = wred(eps2);
    __shared__ float sp[4], se[4];
    if (lane == 0) { sp[wid] = prior; se[wid] = eps2; }
    __syncthreads();
    if (threadIdx.x == 0) {
        int slot = blockIdx.x & 63;
        atomicAdd(&acc[slot],      (double)(sp[0] + sp[1] + sp[2] + sp[3]));
        atomicAdd(&acc[64 + slot], (double)(se[0] + se[1] + se[2] + se[3]));
    }
}

// bias path: out += bias, bias prior, bias posterior
__global__ __launch_bounds__(256) void k_bias(const float* __restrict__ bmu,
                                              const float* __restrict__ brho,
                                              const float* __restrict__ epsb,
                                              float* __restrict__ out,
                                              double* __restrict__ acc) {
    int t   = blockIdx.x * 256 + threadIdx.x;  // 0..16383, 4 elems each
    int idx = t * 4;
    int o   = idx & 1023;
    float4 eb = ((const float4*)epsb)[t];
    float4 m  = *(const float4*)(bmu + o);
    float4 r  = *(const float4*)(brho + o);
    float4 ov = ((const float4*)out)[t];

    float prior = 0.f, post = 0.f;
#define BCOMP(EC, MC, RC, OC)                                                 \
    {                                                                         \
        float sgb = log1pf(expf(RC));                                         \
        float bv  = fmaf(sgb, EC, MC);                                        \
        OC += bv;                                                             \
        float v2 = bv * bv;                                                   \
        float aa = fmaf(-0.5f, v2, CA);                                       \
        float bb = fmaf(-INV2S2, v2, CB);                                     \
        float dd = fmaf(DSLOPE, v2, DC);                                      \
        prior += fmaxf(aa, bb) + log1pf(expf(-fabsf(dd)));                    \
        post += -LOG_SQRT_2PI_F - logf(sgb) - 0.5f * EC * EC;                 \
    }
    BCOMP(eb.x, m.x, r.x, ov.x)
    BCOMP(eb.y, m.y, r.y, ov.y)
    BCOMP(eb.z, m.z, r.z, ov.z)
    BCOMP(eb.w, m.w, r.w, ov.w)
#undef BCOMP
    ((float4*)out)[t] = ov;

    prior = wred(prior);
    post  = wred(post);
    __shared__ float sp[4], se[4];
    if ((threadIdx.x & 63) == 0) {
        sp[threadIdx.x >> 6] = prior;
        se[threadIdx.x >> 6] = post;
    }
    __syncthreads();
    if (threadIdx.x == 0) {
        atomicAdd(&acc[129], (double)(sp[0] + sp[1] + sp[2] + sp[3]));
        atomicAdd(&acc[130], (double)(se[0] + se[1] + se[2] + se[3]));
    }
}

__global__ void k_fin(const double* __restrict__ acc, float* __restrict__ out) {
    if (threadIdx.x == 0) {
        double pw = 0.0, e2 = 0.0;
        for (int i = 0; i < 64; ++i) { pw += acc[i]; e2 += acc[64 + i]; }
        double log_prior = pw + acc[129];
        double log_post  = -NW_ELEMS * LOG_SQRT_2PI - 64.0 * acc[128]
                           - 0.5 * e2 + acc[130];
        out[NROWS]     = (float)log_prior;
        out[NROWS + 1] = (float)log_post;
    }
}

extern "C" void kernel_launch(void* const* d_in, const int* in_sizes, int n_in,
                              void* d_out, int out_size, void* d_ws, size_t ws_size,
                              hipStream_t stream) {
    const float* x    = (const float*)d_in[0];
    const float* wmu  = (const float*)d_in[1];
    const float* wrho = (const float*)d_in[2];
    const float* bmu  = (const float*)d_in[3];
    const float* brho = (const float*)d_in[4];
    const float* epsw = (const float*)d_in[5];
    const float* epsb = (const float*)d_in[6];
    float* out  = (float*)d_out;
    double* acc = (double*)d_ws;

    k_zero<<<1, 256, 0, stream>>>(acc);
    k_logsig<<<(OUT_ * IN_ / 4) / 256, 256, 0, stream>>>(wrho, acc);
    k_main<<<NROWS / 16, 256, 0, stream>>>(x, wmu, wrho, epsw, out, acc);
    k_bias<<<(NROWS / 4) / 256, 256, 0, stream>>>(bmu, brho, epsb, out, acc);
    k_fin<<<1, 64, 0, stream>>>(acc, out);
}

// Round 2
// 400.606 us; speedup vs baseline: 1.4174x; 1.4174x over previous
//
#include <hip/hip_runtime.h>

// Problem constants
#define B_    64
#define IN_   1024
#define OUT_  1024
#define NROWS (B_ * OUT_)            // 65536

// ---------- math constants ----------
#define LOG2E_F 1.4426950408889634f
#define LN2_F   0.6931471805599453f
#define LN2_D   0.6931471805599453
#define LSQ2PI_D 0.9189385332046727
// log2-domain mixture constants:
// lp1_2 = CA2 + A1_2*w^2 ;  CA2 = log2(0.5) - log2(sqrt(2pi))
#define CA2_D  (-2.3257480647361595)
#define CA2_F  (-2.3257481f)
#define A1_2_D (-0.7213475204444817)   // -0.5*log2(e)
#define A1_2_F (-0.72134752f)
// ndd2 = lp2_2 - lp1_2 = NDS2*w^2 + NDC2
#define NDS2_F (-180336.159f)          // (A2_2 - A1_2), A2_2 = -125000*log2(e)
#define NDC2_F (8.965784284662087f)    // CB2 - CA2 = -log2(0.002)

// acc slot layout (doubles in d_ws), 64-slot spread each:
// s0 [0..63]    soft2_w  (sum of log2(1+2^ndd2) over weights)
// s1 [64..127]  eps2     (sum eps_w^2)
// s2 [128..191] sw2      (sum w^2)
// s3 [192..255] prior2_b (full bias prior, log2 domain)
// s4 [256..319] post_b   (bias posterior partial, ln domain)
// s5 [320..383] logsig2  (sum log2(sigma_w) over (O,I))
#define N_ACC 384

__device__ __forceinline__ float fexp2(float x) {
#if __has_builtin(__builtin_amdgcn_exp2f)
    return __builtin_amdgcn_exp2f(x);
#else
    return exp2f(x);
#endif
}
__device__ __forceinline__ float flog2(float x) {
#if __has_builtin(__builtin_amdgcn_logf)
    return __builtin_amdgcn_logf(x);
#else
    return __log2f(x);
#endif
}
// log2(1 + 2^t)  (t <= ~9 here; exp2 underflow -> exact 0 -> log2(1)=0)
__device__ __forceinline__ float softterm(float t) {
    return flog2(1.0f + fexp2(t));
}
// softplus(r) = ln2 * log2(1 + 2^(r*log2e))
__device__ __forceinline__ float softplusf(float r) {
    return LN2_F * softterm(r * LOG2E_F);
}

__device__ __forceinline__ float wred(float v) {
#pragma unroll
    for (int o = 32; o > 0; o >>= 1) v += __shfl_down(v, o, 64);
    return v;
}

__global__ __launch_bounds__(384) void k_zero(double* __restrict__ acc) {
    int t = threadIdx.x;
    if (t < N_ACC) acc[t] = 0.0;
}

// fused per-element work (weights)
#define COMP(EC, XC, SGC, MUC)                                                \
    {                                                                         \
        float w  = fmaf(SGC, EC, MUC);                                        \
        dot      = fmaf(w, XC, dot);                                          \
        float v2 = w * w;                                                     \
        sw2 += v2;                                                            \
        soft += softterm(fmaf(NDS2_F, v2, NDC2_F));                           \
        ep2 = fmaf(EC, EC, ep2);                                              \
    }

__global__ __launch_bounds__(256) void k_main(const float* __restrict__ x,
                                              const float* __restrict__ wmu,
                                              const float* __restrict__ wrho,
                                              const float* __restrict__ bmu,
                                              const float* __restrict__ brho,
                                              const float* __restrict__ epsw,
                                              const float* __restrict__ epsb,
                                              float* __restrict__ out,
                                              double* __restrict__ acc) {
    const int lane = threadIdx.x & 63;
    const int wid  = threadIdx.x >> 6;
    const int gw   = blockIdx.x * 4 + wid;  // global wave id, 0..16383
    const int o    = gw & 1023;             // output column (fixed per wave)
    const int b0   = gw >> 10;              // 0..15 (uniform per block)

    const float4* mp = (const float4*)(wmu  + (size_t)o * IN_);
    const float4* rp = (const float4*)(wrho + (size_t)o * IN_);

    // hoist sigma & mu for this o (reused for 4 batch rows)
    float4 sg[4], mu[4];
#pragma unroll
    for (int k = 0; k < 4; ++k) {
        float4 r = rp[lane + 64 * k];
        mu[k]    = mp[lane + 64 * k];
        sg[k].x  = softplusf(r.x);
        sg[k].y  = softplusf(r.y);
        sg[k].z  = softplusf(r.z);
        sg[k].w  = softplusf(r.w);
    }

    // sum log2(sigma) over this o-row, only once (b0==0 waves)
    float lsg = 0.f;
    if (b0 == 0) {
#pragma unroll
        for (int k = 0; k < 4; ++k)
            lsg += flog2(sg[k].x) + flog2(sg[k].y) + flog2(sg[k].z) + flog2(sg[k].w);
    }

    // bias hoist on lane 0 (o fixed per wave)
    float sgb = 0.f, l2sgb = 0.f, bm = 0.f;
    if (lane == 0) {
        float rb = brho[o];
        sgb   = softplusf(rb);
        l2sgb = flog2(sgb);
        bm    = bmu[o];
    }

    float soft = 0.f, sw2 = 0.f, ep2 = 0.f, pb2 = 0.f, postb = 0.f;
#pragma unroll
    for (int j = 0; j < 4; ++j) {
        const int b      = b0 + 16 * j;
        const size_t row = ((size_t)b << 10) | (size_t)o;
        const float4* ep = (const float4*)(epsw + row * IN_);
        const float4* xp = (const float4*)(x + ((size_t)b << 10));
        float dot = 0.f;
#pragma unroll
        for (int k = 0; k < 4; ++k) {
            float4 e  = ep[lane + 64 * k];
            float4 xx = xp[lane + 64 * k];
            COMP(e.x, xx.x, sg[k].x, mu[k].x)
            COMP(e.y, xx.y, sg[k].y, mu[k].y)
            COMP(e.z, xx.z, sg[k].z, mu[k].z)
            COMP(e.w, xx.w, sg[k].w, mu[k].w)
        }
        dot = wred(dot);
        if (lane == 0) {
            float eb = epsb[row];
            float bv = fmaf(sgb, eb, bm);
            out[row] = dot + bv;
            float v2b = bv * bv;
            pb2  += fmaf(A1_2_F, v2b, CA2_F) + softterm(fmaf(NDS2_F, v2b, NDC2_F));
            postb += fmaf(-LN2_F, l2sgb, -0.5f * eb * eb);
        }
    }

    soft = wred(soft);
    ep2  = wred(ep2);
    sw2  = wred(sw2);
    if (b0 == 0) lsg = wred(lsg);

    __shared__ float sm[6][4];
    if (lane == 0) {
        sm[0][wid] = soft;
        sm[1][wid] = ep2;
        sm[2][wid] = sw2;
        sm[3][wid] = pb2;
        sm[4][wid] = postb;
        sm[5][wid] = lsg;
    }
    __syncthreads();
    if (threadIdx.x < 6) {
        int s   = threadIdx.x;
        float v = sm[s][0] + sm[s][1] + sm[s][2] + sm[s][3];
        if (s < 5 || blockIdx.x < 256)   // logsig2 only from b0==0 blocks
            atomicAdd(&acc[s * 64 + (blockIdx.x & 63)], (double)v);
    }
}

__global__ void k_fin(const double* __restrict__ acc, float* __restrict__ out) {
    int t = threadIdx.x;  // 64 threads
    double v[6];
#pragma unroll
    for (int s = 0; s < 6; ++s) v[s] = acc[s * 64 + t];
#pragma unroll
    for (int o = 32; o > 0; o >>= 1) {
#pragma unroll
        for (int s = 0; s < 6; ++s) v[s] += __shfl_down(v[s], o, 64);
    }
    if (t == 0) {
        double soft2 = v[0], eps2 = v[1], sw2 = v[2];
        double p2b = v[3], postb = v[4], lsig2 = v[5];
        double NW = 67108864.0;  // B*OUT*IN
        double log_prior = LN2_D * (soft2 + A1_2_D * sw2 + NW * CA2_D + p2b);
        double log_post  = -NW * LSQ2PI_D - 64.0 * (LN2_D * lsig2) - 0.5 * eps2
                           + postb - 65536.0 * LSQ2PI_D;
        out[NROWS]     = (float)log_prior;
        out[NROWS + 1] = (float)log_post;
    }
}

extern "C" void kernel_launch(void* const* d_in, const int* in_sizes, int n_in,
                              void* d_out, int out_size, void* d_ws, size_t ws_size,
                              hipStream_t stream) {
    const float* x    = (const float*)d_in[0];
    const float* wmu  = (const float*)d_in[1];
    const float* wrho = (const float*)d_in[2];
    const float* bmu  = (const float*)d_in[3];
    const float* brho = (const float*)d_in[4];
    const float* epsw = (const float*)d_in[5];
    const float* epsb = (const float*)d_in[6];
    float* out  = (float*)d_out;
    double* acc = (double*)d_ws;

    k_zero<<<1, 384, 0, stream>>>(acc);
    k_main<<<NROWS / 16, 256, 0, stream>>>(x, wmu, wrho, bmu, brho, epsw, epsb, out, acc);
    k_fin<<<1, 64, 0, stream>>>(acc, out);
}

// Round 3
// 372.955 us; speedup vs baseline: 1.5225x; 1.0741x over previous
//
#include <hip/hip_runtime.h>

// Problem constants
#define B_    64
#define IN_   1024
#define OUT_  1024
#define NROWS 65536
#define NBLK  4096      // k_main grid

// ---------- math constants ----------
#define LOG2E_F 1.4426950408889634f
#define LN2_F   0.6931471805599453f
#define LN2_D   0.6931471805599453
#define LSQ2PI_D 0.9189385332046727
// log2-domain mixture constants (see round-2 derivation):
#define CA2_D  (-2.3257480647361595)
#define CA2_F  (-2.3257481f)
#define A1_2_D (-0.7213475204444817)
#define A1_2_F (-0.72134752f)
#define NDS2_F (-180336.159f)
#define NDC2_F (8.965784284662087f)

typedef float f32x4 __attribute__((ext_vector_type(4)));

__device__ __forceinline__ f32x4 ntld(const f32x4* p) {
    return __builtin_nontemporal_load(p);
}
__device__ __forceinline__ float fexp2(float x) {
    return __builtin_amdgcn_exp2f(x);
}
__device__ __forceinline__ float flog2(float x) {
    return __builtin_amdgcn_logf(x);
}
__device__ __forceinline__ float softterm(float t) {  // log2(1+2^t)
    return flog2(1.0f + fexp2(t));
}
__device__ __forceinline__ float softplusf(float r) {
    return LN2_F * softterm(r * LOG2E_F);
}

// fused per-element work (weights)
#define COMP(EC, XC, SGC, MUC, DOT)                                           \
    {                                                                         \
        float w  = fmaf(SGC, EC, MUC);                                        \
        DOT      = fmaf(w, XC, DOT);                                          \
        float v2 = w * w;                                                     \
        sw2 += v2;                                                            \
        soft += softterm(fmaf(NDS2_F, v2, NDC2_F));                           \
        ep2 = fmaf(EC, EC, ep2);                                              \
    }

// one batch row: 16 eps elements per lane, dot into DOT
#define ROWJ(JB, DOT)                                                         \
    {                                                                         \
        const size_t bb_ = (size_t)(b0 + (JB));                               \
        const f32x4* ep  = (const f32x4*)(epsw + (((bb_ << 10) | (size_t)o) << 10)); \
        const f32x4* xp  = (const f32x4*)(x + (bb_ << 10));                   \
        _Pragma("unroll")                                                     \
        for (int k = 0; k < 4; ++k) {                                         \
            f32x4 e  = ntld(ep + lane + 64 * k);                              \
            f32x4 xx = xp[lane + 64 * k];                                     \
            COMP(e.x, xx.x, sg[k].x, mu[k].x, DOT)                            \
            COMP(e.y, xx.y, sg[k].y, mu[k].y, DOT)                            \
            COMP(e.z, xx.z, sg[k].z, mu[k].z, DOT)                            \
            COMP(e.w, xx.w, sg[k].w, mu[k].w, DOT)                            \
        }                                                                     \
    }

__global__ __launch_bounds__(256) void k_main(const float* __restrict__ x,
                                              const float* __restrict__ wmu,
                                              const float* __restrict__ wrho,
                                              const float* __restrict__ bmu,
                                              const float* __restrict__ brho,
                                              const float* __restrict__ epsw,
                                              const float* __restrict__ epsb,
                                              float* __restrict__ out,
                                              float* __restrict__ ws) {
    const int lane = threadIdx.x & 63;
    const int wid  = threadIdx.x >> 6;
    const int gw   = blockIdx.x * 4 + wid;  // 0..16383
    const int o    = gw & 1023;             // output column (fixed per wave)
    const int b0   = gw >> 10;              // 0..15

    const f32x4* mp = (const f32x4*)(wmu  + (size_t)o * IN_);
    const f32x4* rp = (const f32x4*)(wrho + (size_t)o * IN_);

    // hoist sigma & mu for this o (reused for 4 batch rows)
    f32x4 sg[4], mu[4];
#pragma unroll
    for (int k = 0; k < 4; ++k) {
        f32x4 r = rp[lane + 64 * k];
        mu[k]   = mp[lane + 64 * k];
        sg[k].x = softplusf(r.x);
        sg[k].y = softplusf(r.y);
        sg[k].z = softplusf(r.z);
        sg[k].w = softplusf(r.w);
    }

    // sum log2(sigma) over this o-row, once per o (b0==0 waves only)
    float lsg = 0.f;
    if (b0 == 0) {
#pragma unroll
        for (int k = 0; k < 4; ++k)
            lsg += flog2(sg[k].x) + flog2(sg[k].y) + flog2(sg[k].z) + flog2(sg[k].w);
    }

    // bias hoist (wave-uniform o; cheap, no divergence)
    float sgb   = softplusf(brho[o]);
    float l2sgb = flog2(sgb);
    float bm    = bmu[o];

    float dot0 = 0.f, dot1 = 0.f, dot2 = 0.f, dot3 = 0.f;
    float soft = 0.f, sw2 = 0.f, ep2 = 0.f;

    ROWJ(0,  dot0)
    ROWJ(16, dot1)
    ROWJ(32, dot2)
    ROWJ(48, dot3)

    // bias per row: lanes 0..3 own rows b0+16*lane (off the hot loop)
    float bv = 0.f, pb2 = 0.f, postb = 0.f;
    const int bb = b0 + 16 * lane;
    if (lane < 4) {
        float eb  = epsb[((size_t)bb << 10) | (size_t)o];
        bv        = fmaf(sgb, eb, bm);
        float v2b = bv * bv;
        pb2   = fmaf(A1_2_F, v2b, CA2_F) + softterm(fmaf(NDS2_F, v2b, NDC2_F));
        postb = fmaf(-LN2_F, l2sgb, -0.5f * eb * eb);
    }

    // one interleaved butterfly for all 10 values (ILP across chains)
#pragma unroll
    for (int off = 32; off; off >>= 1) {
        dot0 += __shfl_xor(dot0, off, 64);
        dot1 += __shfl_xor(dot1, off, 64);
        dot2 += __shfl_xor(dot2, off, 64);
        dot3 += __shfl_xor(dot3, off, 64);
        soft += __shfl_xor(soft, off, 64);
        sw2  += __shfl_xor(sw2,  off, 64);
        ep2  += __shfl_xor(ep2,  off, 64);
        lsg  += __shfl_xor(lsg,  off, 64);
        pb2  += __shfl_xor(pb2,  off, 64);
        postb+= __shfl_xor(postb,off, 64);
    }

    if (lane < 4) {
        float d = (lane == 0) ? dot0 : (lane == 1) ? dot1 : (lane == 2) ? dot2 : dot3;
        out[((size_t)bb << 10) | (size_t)o] = d + bv;
    }

    // block combine -> per-block slots in ws (no atomics, no zero-init needed)
    __shared__ float sm[6][4];
    if (lane == 0) {
        sm[0][wid] = soft;
        sm[1][wid] = ep2;
        sm[2][wid] = sw2;
        sm[3][wid] = pb2;
        sm[4][wid] = postb;
        sm[5][wid] = lsg;   // zero for b0!=0 waves
    }
    __syncthreads();
    if (threadIdx.x < 6) {
        int s = threadIdx.x;
        ws[s * NBLK + blockIdx.x] = sm[s][0] + sm[s][1] + sm[s][2] + sm[s][3];
    }
}

__global__ __launch_bounds__(256) void k_fin(const float* __restrict__ ws,
                                             float* __restrict__ out) {
    const int t    = threadIdx.x;
    const int lane = t & 63;
    const int wid  = t >> 6;
    double a[6] = {0, 0, 0, 0, 0, 0};
    for (int i = 0; i < 16; ++i) {
        int idx = t + 256 * i;
#pragma unroll
        for (int s = 0; s < 6; ++s) a[s] += (double)ws[s * NBLK + idx];
    }
#pragma unroll
    for (int off = 32; off; off >>= 1) {
#pragma unroll
        for (int s = 0; s < 6; ++s) a[s] += __shfl_xor(a[s], off, 64);
    }
    __shared__ double sm[6][4];
    if (lane == 0) {
#pragma unroll
        for (int s = 0; s < 6; ++s) sm[s][wid] = a[s];
    }
    __syncthreads();
    if (t == 0) {
        double v[6];
#pragma unroll
        for (int s = 0; s < 6; ++s)
            v[s] = sm[s][0] + sm[s][1] + sm[s][2] + sm[s][3];
        double soft2 = v[0], eps2 = v[1], sw2 = v[2];
        double p2b = v[3], postb = v[4], lsig2 = v[5];
        const double NW = 67108864.0;  // B*OUT*IN
        double log_prior = LN2_D * (soft2 + A1_2_D * sw2 + NW * CA2_D + p2b);
        double log_post  = -NW * LSQ2PI_D - 64.0 * (LN2_D * lsig2) - 0.5 * eps2
                           + postb - 65536.0 * LSQ2PI_D;
        out[NROWS]     = (float)log_prior;
        out[NROWS + 1] = (float)log_post;
    }
}

extern "C" void kernel_launch(void* const* d_in, const int* in_sizes, int n_in,
                              void* d_out, int out_size, void* d_ws, size_t ws_size,
                              hipStream_t stream) {
    const float* x    = (const float*)d_in[0];
    const float* wmu  = (const float*)d_in[1];
    const float* wrho = (const float*)d_in[2];
    const float* bmu  = (const float*)d_in[3];
    const float* brho = (const float*)d_in[4];
    const float* epsw = (const float*)d_in[5];
    const float* epsb = (const float*)d_in[6];
    float* out = (float*)d_out;
    float* ws  = (float*)d_ws;

    k_main<<<NBLK, 256, 0, stream>>>(x, wmu, wrho, bmu, brho, epsw, epsb, out, ws);
    k_fin<<<1, 256, 0, stream>>>(ws, out);
}